// Round 1
// baseline (890.258 us; speedup 1.0000x reference)
//
#include <hip/hip_runtime.h>

#define L_SEQ 4096
#define NSTEP 2047
#define LR 0.01f

// ---------------------------------------------------------------------------
// Phase A: encoder collapses to a 64-entry table: table[v] = LN(e_v + MLP(e_v))
// ---------------------------------------------------------------------------
__global__ __launch_bounds__(64) void build_table_kernel(
    const float* __restrict__ embed, const float* __restrict__ ff1_w,
    const float* __restrict__ ff1_b, const float* __restrict__ ff2_w,
    const float* __restrict__ ff2_b, const float* __restrict__ ln_g,
    const float* __restrict__ ln_b, float* __restrict__ table)
{
    const int v = threadIdx.x;  // 0..63 vocab id
    float h[32], f[32];
#pragma unroll
    for (int j = 0; j < 32; ++j) { h[j] = embed[v * 32 + j]; f[j] = 0.f; }
    for (int k = 0; k < 64; ++k) {
        float z = ff1_b[k];
#pragma unroll
        for (int j = 0; j < 32; ++j) z += h[j] * ff1_w[k * 32 + j];
        z = fmaxf(z, 0.f);
#pragma unroll
        for (int j = 0; j < 32; ++j) f[j] += z * ff2_w[j * 64 + k];
    }
    float x[32], mu = 0.f;
#pragma unroll
    for (int j = 0; j < 32; ++j) { x[j] = h[j] + f[j] + ff2_b[j]; mu += x[j]; }
    mu *= (1.f / 32.f);
    float var = 0.f;
#pragma unroll
    for (int j = 0; j < 32; ++j) { float d = x[j] - mu; var += d * d; }
    var *= (1.f / 32.f);
    const float inv = rsqrtf(var + 1e-5f);
#pragma unroll
    for (int j = 0; j < 32; ++j)
        table[v * 32 + j] = ln_g[j] * (x[j] - mu) * inv + ln_b[j];
}

// ---------------------------------------------------------------------------
// Phase B: sequential fast-weight scan. One wave64 per batch row.
// Lane layout: i = tid&7 (MLP_INNER row), g = tid>>3 (4 hidden comps 4g..4g+3)
//   lane holds W1[i,4g..4g+3], W2[4g..4g+3,i], b1[i], b2[4g..4g+3], ssum[4g..]
// ---------------------------------------------------------------------------
__global__ __launch_bounds__(64) void scan_kernel(
    const int* __restrict__ seq, const float* __restrict__ table_g,
    const float* __restrict__ fc1_w, const float* __restrict__ fc1_b,
    const float* __restrict__ fc2_w, const float* __restrict__ fc2_b,
    const float* __restrict__ out_w, const float* __restrict__ out_b,
    float* __restrict__ out, float* __restrict__ wacc)
{
    __shared__ float tab[64][32];
    __shared__ float ctx_s[32];
    const int b   = blockIdx.x;
    const int tid = threadIdx.x;
    const int i   = tid & 7;
    const int g   = tid >> 3;

    for (int idx = tid; idx < 2048; idx += 64)
        (&tab[0][0])[idx] = table_g[idx];
    __syncthreads();

    // --- init state ---
    float4 W1r = reinterpret_cast<const float4*>(fc1_w)[i * 8 + g];
    float  b1  = fc1_b[i];
    float  W2r0 = fc2_w[(4 * g + 0) * 8 + i];
    float  W2r1 = fc2_w[(4 * g + 1) * 8 + i];
    float  W2r2 = fc2_w[(4 * g + 2) * 8 + i];
    float  W2r3 = fc2_w[(4 * g + 3) * 8 + i];
    float4 b2r = reinterpret_cast<const float4*>(fc2_b)[g];
    float4 ssum = make_float4(0.f, 0.f, 0.f, 0.f);
    float  nw = 0.f;

    const int2* srow = reinterpret_cast<const int2*>(seq + b * L_SEQ);
    const float4* tab4 = reinterpret_cast<const float4*>(&tab[0][0]);

    int2 tka = srow[0];
    int2 tkb = srow[1];
    float4 kc = tab4[tka.x * 8 + g];
    float4 vc = tab4[tka.y * 8 + g];

    for (int t = 0; t < NSTEP; ++t) {
        // prefetch tokens for t+2 and k/v vectors for t+1
        int2 tkc = srow[(t + 2 < 2048) ? (t + 2) : 2047];
        float4 kn = tab4[tkb.x * 8 + g];
        float4 vn = tab4[tkb.y * 8 + g];

        // --- surprise distance (independent of W): uses pre-update ssum ---
        const float cntm = (t > 1) ? (float)t : 1.0f;   // max(cnt,1), cnt = t
        const float rc = 1.0f / cntm;
        float d0 = kc.x - ssum.x * rc;
        float d1 = kc.y - ssum.y * rc;
        float d2 = kc.z - ssum.z * rc;
        float d3 = kc.w - ssum.w * rc;
        float dd = d0 * d0 + d1 * d1 + d2 * d2 + d3 * d3;
        dd += __shfl_xor(dd, 8); dd += __shfl_xor(dd, 16); dd += __shfl_xor(dd, 32);
        const bool wr = (t == 0) || (dd > 16.0f);   // dist>4 <=> dist^2>16

        // --- z1[i] = W1[i,:]·k + b1 : partial over 4 comps, reduce over g ---
        float zp = W1r.x * kc.x + W1r.y * kc.y + W1r.z * kc.z + W1r.w * kc.w;
        zp += __shfl_xor(zp, 8); zp += __shfl_xor(zp, 16); zp += __shfl_xor(zp, 32);
        const float z1 = zp + b1;
        const float a  = fmaxf(z1, 0.f);

        // --- pred[4g+r] = sum_i W2[4g+r,i]*a[i] + b2 : reduce over i ---
        float p0 = W2r0 * a, p1 = W2r1 * a, p2 = W2r2 * a, p3 = W2r3 * a;
        p0 += __shfl_xor(p0, 1); p0 += __shfl_xor(p0, 2); p0 += __shfl_xor(p0, 4);
        p1 += __shfl_xor(p1, 1); p1 += __shfl_xor(p1, 2); p1 += __shfl_xor(p1, 4);
        p2 += __shfl_xor(p2, 1); p2 += __shfl_xor(p2, 2); p2 += __shfl_xor(p2, 4);
        p3 += __shfl_xor(p3, 1); p3 += __shfl_xor(p3, 2); p3 += __shfl_xor(p3, 4);
        const float dp0 = (p0 + b2r.x - vc.x) * 0.0625f;   // 2/H = 2/32
        const float dp1 = (p1 + b2r.y - vc.y) * 0.0625f;
        const float dp2 = (p2 + b2r.z - vc.z) * 0.0625f;
        const float dp3 = (p3 + b2r.w - vc.w) * 0.0625f;

        // --- dz1[i] = (W2^T dpred)[i] * (z1>0) : reduce over g ---
        float q = W2r0 * dp0 + W2r1 * dp1 + W2r2 * dp2 + W2r3 * dp3;
        q += __shfl_xor(q, 8); q += __shfl_xor(q, 16); q += __shfl_xor(q, 32);
        const float dz1 = (z1 > 0.f) ? q : 0.f;

        if (wr) {   // wave-uniform branch
            W1r.x -= LR * dz1 * kc.x; W1r.y -= LR * dz1 * kc.y;
            W1r.z -= LR * dz1 * kc.z; W1r.w -= LR * dz1 * kc.w;
            b1 -= LR * dz1;
            W2r0 -= LR * dp0 * a; W2r1 -= LR * dp1 * a;
            W2r2 -= LR * dp2 * a; W2r3 -= LR * dp3 * a;
            b2r.x -= LR * dp0; b2r.y -= LR * dp1;
            b2r.z -= LR * dp2; b2r.w -= LR * dp3;
            nw += 1.f;
        }
        ssum.x += kc.x; ssum.y += kc.y; ssum.z += kc.z; ssum.w += kc.w;
        kc = kn; vc = vn; tka = tkb; tkb = tkc;
    }

    // --- query/context: query = table[seq[b, L-1]] ---
    const int tq = seq[b * L_SEQ + (L_SEQ - 1)];
    float4 kq = tab4[tq * 8 + g];
    float zq = W1r.x * kq.x + W1r.y * kq.y + W1r.z * kq.z + W1r.w * kq.w;
    zq += __shfl_xor(zq, 8); zq += __shfl_xor(zq, 16); zq += __shfl_xor(zq, 32);
    const float aq = fmaxf(zq + b1, 0.f);
    float c0 = W2r0 * aq, c1 = W2r1 * aq, c2 = W2r2 * aq, c3 = W2r3 * aq;
    c0 += __shfl_xor(c0, 1); c0 += __shfl_xor(c0, 2); c0 += __shfl_xor(c0, 4);
    c1 += __shfl_xor(c1, 1); c1 += __shfl_xor(c1, 2); c1 += __shfl_xor(c1, 4);
    c2 += __shfl_xor(c2, 1); c2 += __shfl_xor(c2, 2); c2 += __shfl_xor(c2, 4);
    c3 += __shfl_xor(c3, 1); c3 += __shfl_xor(c3, 2); c3 += __shfl_xor(c3, 4);
    if (i == 0) {
        ctx_s[4 * g + 0] = c0 + b2r.x;
        ctx_s[4 * g + 1] = c1 + b2r.y;
        ctx_s[4 * g + 2] = c2 + b2r.z;
        ctx_s[4 * g + 3] = c3 + b2r.w;
    }
    __syncthreads();

    // --- logits[b, tid] = ctx · out_w[tid,:] + out_b[tid] ---
    float acc = out_b[tid];
#pragma unroll
    for (int j = 0; j < 32; ++j) acc += ctx_s[j] * out_w[tid * 32 + j];
    out[b * 64 + tid] = acc;

    if (tid == 0) atomicAdd(wacc, nw);  // nw integer-valued: exact float sum
}

__global__ void finalize_kernel(const float* __restrict__ wacc,
                                float* __restrict__ out)
{
    out[16384] = wacc[0] / 524032.0f;   // / (B * n) = 256 * 2047
}

// ---------------------------------------------------------------------------
extern "C" void kernel_launch(void* const* d_in, const int* in_sizes, int n_in,
                              void* d_out, int out_size, void* d_ws, size_t ws_size,
                              hipStream_t stream)
{
    const int*   seq   = (const int*)  d_in[0];
    const float* embed = (const float*)d_in[1];
    const float* ff1_w = (const float*)d_in[2];
    const float* ff1_b = (const float*)d_in[3];
    const float* ff2_w = (const float*)d_in[4];
    const float* ff2_b = (const float*)d_in[5];
    const float* ln_g  = (const float*)d_in[6];
    const float* ln_b  = (const float*)d_in[7];
    const float* fc1_w = (const float*)d_in[8];
    const float* fc1_b = (const float*)d_in[9];
    const float* fc2_w = (const float*)d_in[10];
    const float* fc2_b = (const float*)d_in[11];
    const float* out_w = (const float*)d_in[12];
    const float* out_b = (const float*)d_in[13];

    float* out   = (float*)d_out;
    float* table = (float*)d_ws;                      // 2048 floats (8 KiB)
    float* wacc  = (float*)((char*)d_ws + 8192);      // 1 float accumulator

    hipMemsetAsync(wacc, 0, sizeof(float), stream);
    hipLaunchKernelGGL(build_table_kernel, dim3(1), dim3(64), 0, stream,
                       embed, ff1_w, ff1_b, ff2_w, ff2_b, ln_g, ln_b, table);
    hipLaunchKernelGGL(scan_kernel, dim3(256), dim3(64), 0, stream,
                       seq, table, fc1_w, fc1_b, fc2_w, fc2_b,
                       out_w, out_b, out, wacc);
    hipLaunchKernelGGL(finalize_kernel, dim3(1), dim3(1), 0, stream, wacc, out);
}

// Round 2
// 521.083 us; speedup vs baseline: 1.7085x; 1.7085x over previous
//
#include <hip/hip_runtime.h>

#define L_SEQ 4096
#define NSTEP 2047
#define LR 0.01f

// ---------------------------------------------------------------------------
// Cross-lane reduction helpers (VALU pipe: DPP + permlane, not LDS shuffles).
// Layout: i = lane&7, g = lane>>3.
//  redi4: sum over i (lanes xor 1,2,4) for 4 independent values.
//         quad_perm xor1, quad_perm xor2, then row_half_mirror (valid because
//         after two stages each quad is uniform; mirror fetches other quad).
//  redg*: sum over g (lanes xor 8,16,32): row_ror:8 == xor8 within a 16-row;
//         permlane16_swap / permlane32_swap butterflies (t=x symmetric init
//         makes swap-direction irrelevant: sum = both halves either way).
// s_nop 1 guards the gfx9 VALU-write -> DPP-read wait-state hazard (invisible
// to the compiler inside asm).
// ---------------------------------------------------------------------------
__device__ __forceinline__ void redi4(float& a, float& b, float& c, float& d) {
    asm volatile(
        "s_nop 1\n\t"
        "v_add_f32_dpp %0, %0, %0 quad_perm:[1,0,3,2] row_mask:0xf bank_mask:0xf bound_ctrl:0\n\t"
        "v_add_f32_dpp %1, %1, %1 quad_perm:[1,0,3,2] row_mask:0xf bank_mask:0xf bound_ctrl:0\n\t"
        "v_add_f32_dpp %2, %2, %2 quad_perm:[1,0,3,2] row_mask:0xf bank_mask:0xf bound_ctrl:0\n\t"
        "v_add_f32_dpp %3, %3, %3 quad_perm:[1,0,3,2] row_mask:0xf bank_mask:0xf bound_ctrl:0\n\t"
        "v_add_f32_dpp %0, %0, %0 quad_perm:[2,3,0,1] row_mask:0xf bank_mask:0xf bound_ctrl:0\n\t"
        "v_add_f32_dpp %1, %1, %1 quad_perm:[2,3,0,1] row_mask:0xf bank_mask:0xf bound_ctrl:0\n\t"
        "v_add_f32_dpp %2, %2, %2 quad_perm:[2,3,0,1] row_mask:0xf bank_mask:0xf bound_ctrl:0\n\t"
        "v_add_f32_dpp %3, %3, %3 quad_perm:[2,3,0,1] row_mask:0xf bank_mask:0xf bound_ctrl:0\n\t"
        "v_add_f32_dpp %0, %0, %0 row_half_mirror row_mask:0xf bank_mask:0xf bound_ctrl:0\n\t"
        "v_add_f32_dpp %1, %1, %1 row_half_mirror row_mask:0xf bank_mask:0xf bound_ctrl:0\n\t"
        "v_add_f32_dpp %2, %2, %2 row_half_mirror row_mask:0xf bank_mask:0xf bound_ctrl:0\n\t"
        "v_add_f32_dpp %3, %3, %3 row_half_mirror row_mask:0xf bank_mask:0xf bound_ctrl:0"
        : "+v"(a), "+v"(b), "+v"(c), "+v"(d));
}

__device__ __forceinline__ void redg2(float& x, float& y) {
    float t0, t1;
    asm volatile(
        "s_nop 1\n\t"
        "v_add_f32_dpp %0, %0, %0 row_ror:8 row_mask:0xf bank_mask:0xf bound_ctrl:0\n\t"
        "v_add_f32_dpp %1, %1, %1 row_ror:8 row_mask:0xf bank_mask:0xf bound_ctrl:0\n\t"
        "v_mov_b32 %2, %0\n\t"
        "v_mov_b32 %3, %1\n\t"
        "s_nop 0\n\t"
        "v_permlane16_swap_b32 %2, %0\n\t"
        "v_permlane16_swap_b32 %3, %1\n\t"
        "v_add_f32 %0, %0, %2\n\t"
        "v_add_f32 %1, %1, %3\n\t"
        "v_mov_b32 %2, %0\n\t"
        "v_mov_b32 %3, %1\n\t"
        "s_nop 0\n\t"
        "v_permlane32_swap_b32 %2, %0\n\t"
        "v_permlane32_swap_b32 %3, %1\n\t"
        "v_add_f32 %0, %0, %2\n\t"
        "v_add_f32 %1, %1, %3"
        : "+v"(x), "+v"(y), "=&v"(t0), "=&v"(t1));
}

__device__ __forceinline__ float redg1(float x) {
    float t;
    asm volatile(
        "s_nop 1\n\t"
        "v_add_f32_dpp %0, %0, %0 row_ror:8 row_mask:0xf bank_mask:0xf bound_ctrl:0\n\t"
        "s_nop 1\n\t"
        "v_mov_b32 %1, %0\n\t"
        "s_nop 1\n\t"
        "v_permlane16_swap_b32 %1, %0\n\t"
        "s_nop 0\n\t"
        "v_add_f32 %0, %0, %1\n\t"
        "s_nop 1\n\t"
        "v_mov_b32 %1, %0\n\t"
        "s_nop 1\n\t"
        "v_permlane32_swap_b32 %1, %0\n\t"
        "s_nop 0\n\t"
        "v_add_f32 %0, %0, %1"
        : "+v"(x), "=&v"(t));
    return x;
}

// ---------------------------------------------------------------------------
// Phase A: encoder collapses to a 64-entry table: table[v] = LN(e_v + MLP(e_v))
// ---------------------------------------------------------------------------
__global__ __launch_bounds__(64) void build_table_kernel(
    const float* __restrict__ embed, const float* __restrict__ ff1_w,
    const float* __restrict__ ff1_b, const float* __restrict__ ff2_w,
    const float* __restrict__ ff2_b, const float* __restrict__ ln_g,
    const float* __restrict__ ln_b, float* __restrict__ table)
{
    const int v = threadIdx.x;  // 0..63 vocab id
    float h[32], f[32];
#pragma unroll
    for (int j = 0; j < 32; ++j) { h[j] = embed[v * 32 + j]; f[j] = 0.f; }
    for (int k = 0; k < 64; ++k) {
        float z = ff1_b[k];
#pragma unroll
        for (int j = 0; j < 32; ++j) z += h[j] * ff1_w[k * 32 + j];
        z = fmaxf(z, 0.f);
#pragma unroll
        for (int j = 0; j < 32; ++j) f[j] += z * ff2_w[j * 64 + k];
    }
    float x[32], mu = 0.f;
#pragma unroll
    for (int j = 0; j < 32; ++j) { x[j] = h[j] + f[j] + ff2_b[j]; mu += x[j]; }
    mu *= (1.f / 32.f);
    float var = 0.f;
#pragma unroll
    for (int j = 0; j < 32; ++j) { float d = x[j] - mu; var += d * d; }
    var *= (1.f / 32.f);
    const float inv = rsqrtf(var + 1e-5f);
#pragma unroll
    for (int j = 0; j < 32; ++j)
        table[v * 32 + j] = ln_g[j] * (x[j] - mu) * inv + ln_b[j];
}

// ---------------------------------------------------------------------------
// Phase B: sequential fast-weight scan. One wave64 per batch row.
// Lane layout: i = tid&7 (MLP_INNER row), g = tid>>3 (4 hidden comps 4g..4g+3)
// ---------------------------------------------------------------------------
__global__ __launch_bounds__(64) void scan_kernel(
    const int* __restrict__ seq, const float* __restrict__ table_g,
    const float* __restrict__ fc1_w, const float* __restrict__ fc1_b,
    const float* __restrict__ fc2_w, const float* __restrict__ fc2_b,
    const float* __restrict__ out_w, const float* __restrict__ out_b,
    float* __restrict__ out, float* __restrict__ wacc)
{
    __shared__ float tab[64][32];
    __shared__ float ctx_s[32];
    const int b   = blockIdx.x;
    const int tid = threadIdx.x;
    const int i   = tid & 7;
    const int g   = tid >> 3;

    for (int idx = tid; idx < 2048; idx += 64)
        (&tab[0][0])[idx] = table_g[idx];
    __syncthreads();

    // --- init state ---
    float4 W1r = reinterpret_cast<const float4*>(fc1_w)[i * 8 + g];
    float  b1  = fc1_b[i];
    float  W2r0 = fc2_w[(4 * g + 0) * 8 + i];
    float  W2r1 = fc2_w[(4 * g + 1) * 8 + i];
    float  W2r2 = fc2_w[(4 * g + 2) * 8 + i];
    float  W2r3 = fc2_w[(4 * g + 3) * 8 + i];
    float4 b2r = reinterpret_cast<const float4*>(fc2_b)[g];
    float4 ssum = make_float4(0.f, 0.f, 0.f, 0.f);
    float  nw = 0.f;
    float  cntf = 0.f;   // == t

    const int2* srow = reinterpret_cast<const int2*>(seq + b * L_SEQ);
    const float4* tab4 = reinterpret_cast<const float4*>(&tab[0][0]);

    int2 tkb = srow[1];
    {
        int2 tka = srow[0];
        (void)tka;
    }
    int2 tka0 = srow[0];
    float4 kc = tab4[tka0.x * 8 + g];
    float4 vc = tab4[tka0.y * 8 + g];

#pragma unroll 2
    for (int t = 0; t < NSTEP; ++t) {
        // prefetch tokens for t+2 and k/v vectors for t+1
        int2 tkc = srow[(t + 2 < 2048) ? (t + 2) : 2047];
        float4 kn = tab4[tkb.x * 8 + g];
        float4 vn = tab4[tkb.y * 8 + g];

        // --- surprise distance (uses pre-update ssum; per-lane partial over g)
        const float cntm = fmaxf(cntf, 1.0f);
        const float mrc  = -__builtin_amdgcn_rcpf(cntm);
        float d0 = fmaf(ssum.x, mrc, kc.x);
        float d1 = fmaf(ssum.y, mrc, kc.y);
        float d2 = fmaf(ssum.z, mrc, kc.z);
        float d3 = fmaf(ssum.w, mrc, kc.w);
        float dd = (d0 * d0 + d1 * d1) + (d2 * d2 + d3 * d3);

        // --- z1 partial: W1[i,4g..4g+3] . k ---
        float zp = W1r.x * kc.x + W1r.y * kc.y + W1r.z * kc.z + W1r.w * kc.w;

        redg2(dd, zp);                       // both reduced over g

        const bool wr = (cntf == 0.0f) || (dd > 16.0f);  // dist>4 <=> dist^2>16
        const float z1 = zp + b1;
        const float a  = fmaxf(z1, 0.f);

        // off-path: es_c = (b2-v)*2/H, so dp = fma(p, s, es)
        const float es0 = (b2r.x - vc.x) * 0.0625f;
        const float es1 = (b2r.y - vc.y) * 0.0625f;
        const float es2 = (b2r.z - vc.z) * 0.0625f;
        const float es3 = (b2r.w - vc.w) * 0.0625f;

        // --- pred partials, reduce over i ---
        float p0 = W2r0 * a, p1 = W2r1 * a, p2 = W2r2 * a, p3 = W2r3 * a;
        redi4(p0, p1, p2, p3);
        const float dp0 = fmaf(p0, 0.0625f, es0);
        const float dp1 = fmaf(p1, 0.0625f, es1);
        const float dp2 = fmaf(p2, 0.0625f, es2);
        const float dp3 = fmaf(p3, 0.0625f, es3);

        // --- dz1 partial: (W2^T dpred)[i], reduce over g ---
        float qa = fmaf(W2r0, dp0, W2r1 * dp1);
        float qb = fmaf(W2r2, dp2, W2r3 * dp3);
        float q  = redg1(qa + qb);
        const float dz1 = (z1 > 0.f) ? q : 0.f;

        if (wr) {   // wave-uniform branch
            const float v1 = -LR * dz1;
            W1r.x = fmaf(v1, kc.x, W1r.x); W1r.y = fmaf(v1, kc.y, W1r.y);
            W1r.z = fmaf(v1, kc.z, W1r.z); W1r.w = fmaf(v1, kc.w, W1r.w);
            b1 += v1;
            const float u0 = -LR * dp0, u1 = -LR * dp1, u2 = -LR * dp2, u3 = -LR * dp3;
            W2r0 = fmaf(u0, a, W2r0); W2r1 = fmaf(u1, a, W2r1);
            W2r2 = fmaf(u2, a, W2r2); W2r3 = fmaf(u3, a, W2r3);
            b2r.x += u0; b2r.y += u1; b2r.z += u2; b2r.w += u3;
            nw += 1.f;
        }
        ssum.x += kc.x; ssum.y += kc.y; ssum.z += kc.z; ssum.w += kc.w;
        cntf += 1.0f;
        kc = kn; vc = vn; tkb = tkc;
    }

    // --- query/context: query = table[seq[b, L-1]] ---
    const int tq = seq[b * L_SEQ + (L_SEQ - 1)];
    float4 kq = tab4[tq * 8 + g];
    float zq = W1r.x * kq.x + W1r.y * kq.y + W1r.z * kq.z + W1r.w * kq.w;
    zq = redg1(zq);
    const float aq = fmaxf(zq + b1, 0.f);
    float c0 = W2r0 * aq, c1 = W2r1 * aq, c2 = W2r2 * aq, c3 = W2r3 * aq;
    redi4(c0, c1, c2, c3);
    if (i == 0) {
        ctx_s[4 * g + 0] = c0 + b2r.x;
        ctx_s[4 * g + 1] = c1 + b2r.y;
        ctx_s[4 * g + 2] = c2 + b2r.z;
        ctx_s[4 * g + 3] = c3 + b2r.w;
    }
    __syncthreads();

    // --- logits[b, tid] = ctx . out_w[tid,:] + out_b[tid] ---
    float acc = out_b[tid];
#pragma unroll
    for (int j = 0; j < 32; ++j) acc += ctx_s[j] * out_w[tid * 32 + j];
    out[b * 64 + tid] = acc;

    if (tid == 0) atomicAdd(wacc, nw);  // nw integer-valued: exact float sum
}

__global__ void finalize_kernel(const float* __restrict__ wacc,
                                float* __restrict__ out)
{
    out[16384] = wacc[0] / 524032.0f;   // / (B * n) = 256 * 2047
}

// ---------------------------------------------------------------------------
extern "C" void kernel_launch(void* const* d_in, const int* in_sizes, int n_in,
                              void* d_out, int out_size, void* d_ws, size_t ws_size,
                              hipStream_t stream)
{
    const int*   seq   = (const int*)  d_in[0];
    const float* embed = (const float*)d_in[1];
    const float* ff1_w = (const float*)d_in[2];
    const float* ff1_b = (const float*)d_in[3];
    const float* ff2_w = (const float*)d_in[4];
    const float* ff2_b = (const float*)d_in[5];
    const float* ln_g  = (const float*)d_in[6];
    const float* ln_b  = (const float*)d_in[7];
    const float* fc1_w = (const float*)d_in[8];
    const float* fc1_b = (const float*)d_in[9];
    const float* fc2_w = (const float*)d_in[10];
    const float* fc2_b = (const float*)d_in[11];
    const float* out_w = (const float*)d_in[12];
    const float* out_b = (const float*)d_in[13];

    float* out   = (float*)d_out;
    float* table = (float*)d_ws;                      // 2048 floats (8 KiB)
    float* wacc  = (float*)((char*)d_ws + 8192);      // 1 float accumulator

    hipMemsetAsync(wacc, 0, sizeof(float), stream);
    hipLaunchKernelGGL(build_table_kernel, dim3(1), dim3(64), 0, stream,
                       embed, ff1_w, ff1_b, ff2_w, ff2_b, ln_g, ln_b, table);
    hipLaunchKernelGGL(scan_kernel, dim3(256), dim3(64), 0, stream,
                       seq, table, fc1_w, fc1_b, fc2_w, fc2_b,
                       out_w, out_b, out, wacc);
    hipLaunchKernelGGL(finalize_kernel, dim3(1), dim3(1), 0, stream, wacc, out);
}